// Round 9
// baseline (147.256 us; speedup 1.0000x reference)
//
#include <hip/hip_runtime.h>
#include <hip/hip_bf16.h>
#include <math.h>

#define BB 2
#define SS 4096
#define HH 768
#define NHEADS 12
#define MTOT (BB*SS)     // 8192
#define NQKV (3*HH)      // 2304

typedef _Float16 f16;
typedef __attribute__((ext_vector_type(8))) _Float16 f16x8;
typedef __attribute__((ext_vector_type(4))) _Float16 f16x4;
typedef __attribute__((ext_vector_type(4))) float f32x4;

__device__ __forceinline__ void gld_lds16(const void* g, void* l) {
  __builtin_amdgcn_global_load_lds(
      (const __attribute__((address_space(1))) unsigned int*)g,
      (__attribute__((address_space(3))) unsigned int*)l, 16, 0, 0);
}

// ---------------- f32 -> f16 convert -------------------------------------
__global__ __launch_bounds__(256)
void cvt_kernel(const float* __restrict__ src, f16* __restrict__ dst, int n4) {
  int i = blockIdx.x * 256 + threadIdx.x;
  if (i >= n4) return;
  float4 v = reinterpret_cast<const float4*>(src)[i];
  f16x4 o;
  o[0] = (f16)v.x; o[1] = (f16)v.y; o[2] = (f16)v.z; o[3] = (f16)v.w;
  reinterpret_cast<f16x4*>(dst)[i] = o;
}

// ---------------- RoPE cos/sin table (f64 phase) -------------------------
__global__ void rope_table_kernel(float* __restrict__ ctab, float* __restrict__ stab) {
  int idx = blockIdx.x * 256 + threadIdx.x;   // 4096*32
  if (idx >= SS * 32) return;
  int s = idx >> 5;
  int j = idx & 31;
  const double r = 0.7498942093324559;  // 10000^(-1/32)
  double inv = 1.0;
  for (int t = 0; t < j; ++t) inv *= r;
  double ph = (double)s * inv;
  const double TWO_PI = 6.283185307179586;
  double red = ph - TWO_PI * floor(ph / TWO_PI);
  float rf = (float)red;
  ctab[idx] = cosf(rf);
  stab[idx] = sinf(rf);
}

// ---------------- f16 MFMA GEMM, BK=64, 2-buffer counted-vmcnt -----------
// C = A * W^T. EPI=0: f32 C. EPI=1: fused RoPE epilogue -> q/k/v f16.
// 64 KB LDS. Per step: 32 MFMA/wave, 8 gld_lds/thread, 2 barriers.
// Swizzle: global chunk g (of 8 per 128B row) stored at physical chunk
// p = g ^ (row & 7); read side applies the same XOR (involution).
template<int EPI>
__global__ __launch_bounds__(256)
void gemm_f16(const f16* __restrict__ A, const f16* __restrict__ Bw,
              float* __restrict__ C,
              f16* __restrict__ Oq, f16* __restrict__ Ok, f16* __restrict__ Ov,
              const int* __restrict__ pos,
              const float* __restrict__ ctab, const float* __restrict__ stab,
              int Mtiles, int N, int K) {
  __shared__ __align__(16) f16 As[2][128][64];   // 32 KB
  __shared__ __align__(16) f16 Bs[2][128][64];   // 32 KB
  const int tid = threadIdx.x;
  const int lane = tid & 63;
  const int w = tid >> 6;
  const int wr = w >> 1, wc = w & 1;

  const int nwg = gridDim.x;
  const int bid = blockIdx.x;
  const int swz = (bid & 7) * (nwg >> 3) + (bid >> 3);
  const int bm = (swz % Mtiles) * 128;
  const int bn = (swz / Mtiles) * 128;

  f32x4 acc[4][4] = {};

  const int sr8 = lane >> 3;         // staging row-sub (0..7)
  const int gsw = (lane & 7) ^ sr8;  // global chunk for phys slot lane&7
  const int srow = w * 32;
  const int fr = lane & 15;          // fragment row within 16

  // stage K-chunk k0 (64 wide) into buffer `buf`: 8 gld_lds per thread
  auto stage = [&](int buf, int k0) {
#pragma unroll
    for (int i = 0; i < 4; ++i) {
      int row = srow + i * 8 + sr8;
      gld_lds16(A + (size_t)(bm + row) * K + k0 + gsw * 8,
                (char*)&As[0][0][0] + buf * 16384 + w * 4096 + i * 1024 + lane * 16);
      gld_lds16(Bw + (size_t)(bn + row) * K + k0 + gsw * 8,
                (char*)&Bs[0][0][0] + buf * 16384 + w * 4096 + i * 1024 + lane * 16);
    }
  };
  auto compute = [&](int buf) {
#pragma unroll
    for (int kk = 0; kk < 2; ++kk) {
      const int po = ((kk * 4 + (lane >> 4)) ^ (lane & 7)) * 8;
      f16x8 av[4], bv[4];
#pragma unroll
      for (int m = 0; m < 4; ++m)
        av[m] = *reinterpret_cast<const f16x8*>(&As[buf][wr * 64 + m * 16 + fr][po]);
#pragma unroll
      for (int n = 0; n < 4; ++n)
        bv[n] = *reinterpret_cast<const f16x8*>(&Bs[buf][wc * 64 + n * 16 + fr][po]);
      __builtin_amdgcn_s_setprio(1);
#pragma unroll
      for (int m = 0; m < 4; ++m)
#pragma unroll
        for (int n = 0; n < 4; ++n)
          acc[m][n] = __builtin_amdgcn_mfma_f32_16x16x32_f16(av[m], bv[n],
                                                             acc[m][n], 0, 0, 0);
      __builtin_amdgcn_s_setprio(0);
    }
  };

  const int T = K >> 6;   // 12 for K=768
  stage(0, 0);
  for (int t = 0; t < T; ++t) {
    if (t + 1 < T) {
      stage((t + 1) & 1, (t + 1) << 6);
      // wait only for stage t; stage t+1's 8 loads stay in flight
      asm volatile("s_waitcnt vmcnt(8)" ::: "memory");
    } else {
      asm volatile("s_waitcnt vmcnt(0)" ::: "memory");
    }
    __builtin_amdgcn_s_barrier();
    __builtin_amdgcn_sched_barrier(0);
    compute(t & 1);
    __builtin_amdgcn_s_barrier();   // protect buf[t&1] from stage t+2
  }

  const int cl = lane & 15;
  const int rg = lane >> 4;
  if (EPI == 0) {
#pragma unroll
    for (int m = 0; m < 4; ++m)
#pragma unroll
      for (int n = 0; n < 4; ++n)
#pragma unroll
        for (int r = 0; r < 4; ++r) {
          int row = bm + wr * 64 + m * 16 + rg * 4 + r;
          int col = bn + wc * 64 + n * 16 + cl;
          C[(size_t)row * N + col] = acc[m][n][r];
        }
  } else {
    const int sec = bn / HH;        // 0=q 1=k 2=v (uniform per block)
    f16* dst = (sec == 0) ? Oq : ((sec == 1) ? Ok : Ov);
    const int hb = bn - sec * HH + wc * 64;
#pragma unroll
    for (int m = 0; m < 4; ++m)
#pragma unroll
      for (int r = 0; r < 4; ++r) {
        int row = bm + wr * 64 + m * 16 + rg * 4 + r;
        if (sec < 2) {
          int s = pos[row];
#pragma unroll
          for (int n = 0; n < 4; ++n) {
            int hd = hb + n * 16 + cl;
            int d = hd & 63;
            int d2 = d & 31;
            float c = ctab[s * 32 + d2];
            float sn = stab[s * 32 + d2];
            float val = acc[m][n][r];
            float pv = acc[m][n ^ 2][r];
            val = (d < 32) ? (val * c - pv * sn) : (val * c + pv * sn);
            if (sec == 0) val *= 0.125f;
            dst[(size_t)row * HH + hd] = (f16)val;
          }
        } else {
#pragma unroll
          for (int n = 0; n < 4; ++n)
            dst[(size_t)row * HH + hb + n * 16 + cl] = (f16)acc[m][n][r];
        }
      }
  }
}

// ---------------- MFMA sliding-window attention --------------------------
// Block: (b, h, 64-query tile). Window keys: [q0-64, q0+127] = 192 rows.
#define AQT 64
#define AKT 192
#define KP 72     // K/Q row pad (f16): 144 B rows
#define VP 200    // Vt / P row pad: 400 B rows

__global__ __launch_bounds__(256)
void attn_kernel(const f16* __restrict__ qg, const f16* __restrict__ kg,
                 const f16* __restrict__ vg, f16* __restrict__ og) {
  __shared__ __align__(16) f16 Qs[AQT][KP];     // 9216 B
  __shared__ __align__(16) f16 Ks[AKT][KP];     // 27648 B, reused for P[64][VP]
  __shared__ __align__(16) f16 Vs[64][VP];      // 25600 B (transposed V)
  __shared__ float sums[AQT];

  const int tid = threadIdx.x;
  const int lane = tid & 63;
  const int wq = tid >> 6;
  const int l15 = lane & 15, g = lane >> 4;
  const int blk = blockIdx.x;
  const int qt = blk % (SS / AQT);
  const int h = (blk / (SS / AQT)) % NHEADS;
  const int b = blk / ((SS / AQT) * NHEADS);
  const int q0 = qt * AQT;
  const int kbase = q0 - 64;

  // ---- stage Q (64x64), K (192x64), V transposed (64x192) ----
#pragma unroll
  for (int i = 0; i < 2; ++i) {
    int idx = tid + i * 256;
    int r = idx >> 3, ch = idx & 7;
    f16x8 v = *reinterpret_cast<const f16x8*>(
        &qg[((size_t)(b * SS + q0 + r)) * HH + h * 64 + ch * 8]);
    *reinterpret_cast<f16x8*>(&Qs[r][ch * 8]) = v;
  }
#pragma unroll
  for (int i = 0; i < 6; ++i) {
    int idx = tid + i * 256;
    int r = idx >> 3, ch = idx & 7;
    int kglob = kbase + r;
    f16x8 v = {};
    if (kglob >= 0 && kglob < SS)
      v = *reinterpret_cast<const f16x8*>(
          &kg[((size_t)(b * SS + kglob)) * HH + h * 64 + ch * 8]);
    *reinterpret_cast<f16x8*>(&Ks[r][ch * 8]) = v;
  }
#pragma unroll
  for (int i = 0; i < 6; ++i) {
    int idx = tid + i * 256;
    int r = idx >> 3, ch = idx & 7;
    int kglob = kbase + r;
    f16x8 v = {};
    if (kglob >= 0 && kglob < SS)
      v = *reinterpret_cast<const f16x8*>(
          &vg[((size_t)(b * SS + kglob)) * HH + h * 64 + ch * 8]);
#pragma unroll
    for (int j = 0; j < 8; ++j) Vs[ch * 8 + j][r] = v[j];
  }
  __syncthreads();

  // ---- S^T = K . Q^T ----
  f32x4 accs[12] = {};
#pragma unroll
  for (int kd = 0; kd < 2; ++kd) {
    f16x8 bq = *reinterpret_cast<const f16x8*>(&Qs[wq * 16 + l15][kd * 32 + g * 8]);
#pragma unroll
    for (int f = 0; f < 12; ++f) {
      f16x8 ak = *reinterpret_cast<const f16x8*>(&Ks[f * 16 + l15][kd * 32 + g * 8]);
      accs[f] = __builtin_amdgcn_mfma_f32_16x16x32_f16(ak, bq, accs[f], 0, 0, 0);
    }
  }
  __syncthreads();   // Ks becomes P storage

  // ---- softmax over keys; lane owns column q = wq*16+l15 ----
  const int qloc = wq * 16 + l15;
  float mx = -1e30f;
#pragma unroll
  for (int f = 0; f < 12; ++f)
#pragma unroll
    for (int r = 0; r < 4; ++r) {
      int key = f * 16 + g * 4 + r;
      int kglob = kbase + key;
      bool valid = (key >= qloc) && (key <= qloc + 128) && (kglob >= 0) && (kglob < SS);
      float s = valid ? accs[f][r] : -1e30f;
      accs[f][r] = s;
      mx = fmaxf(mx, s);
    }
  mx = fmaxf(mx, __shfl_xor(mx, 16));
  mx = fmaxf(mx, __shfl_xor(mx, 32));
  f16* Ps = &Ks[0][0];
  float sum = 0.f;
#pragma unroll
  for (int f = 0; f < 12; ++f) {
    float p0 = __expf(accs[f][0] - mx);
    float p1 = __expf(accs[f][1] - mx);
    float p2 = __expf(accs[f][2] - mx);
    float p3 = __expf(accs[f][3] - mx);
    sum += (p0 + p1) + (p2 + p3);
    f16x4 pk;
    pk[0] = (f16)p0; pk[1] = (f16)p1; pk[2] = (f16)p2; pk[3] = (f16)p3;
    *reinterpret_cast<f16x4*>(&Ps[(size_t)qloc * VP + f * 16 + g * 4]) = pk;
  }
  sum += __shfl_xor(sum, 16);
  sum += __shfl_xor(sum, 32);
  if (g == 0) sums[qloc] = sum;

  // ---- O = P . V ----
  f32x4 acco[4] = {};
#pragma unroll
  for (int ks = 0; ks < 6; ++ks) {
    f16x8 pa = *reinterpret_cast<const f16x8*>(&Ps[(size_t)(wq * 16 + l15) * VP + ks * 32 + g * 8]);
#pragma unroll
    for (int n = 0; n < 4; ++n) {
      f16x8 bv = *reinterpret_cast<const f16x8*>(&Vs[n * 16 + l15][ks * 32 + g * 8]);
      acco[n] = __builtin_amdgcn_mfma_f32_16x16x32_f16(pa, bv, acco[n], 0, 0, 0);
    }
  }
#pragma unroll
  for (int r = 0; r < 4; ++r) {
    int qo = wq * 16 + g * 4 + r;
    float inv = 1.0f / sums[qo];
    size_t base = ((size_t)(b * SS + q0 + qo)) * HH + h * 64;
#pragma unroll
    for (int n = 0; n < 4; ++n)
      og[base + n * 16 + l15] = (f16)(acco[n][r] * inv);
  }
}

extern "C" void kernel_launch(void* const* d_in, const int* in_sizes, int n_in,
                              void* d_out, int out_size, void* d_ws, size_t ws_size,
                              hipStream_t stream) {
  const float* hs = (const float*)d_in[0];
  const int* pos = (const int*)d_in[3];
  const float* Wqkv = (const float*)d_in[4];
  const float* Wo = (const float*)d_in[5];
  float* out = (float*)d_out;

  uint8_t* ws = (uint8_t*)d_ws;
  size_t off = 0;
  float* ctab = (float*)(ws + off); off += (size_t)SS * 32 * 4;
  float* stab = (float*)(ws + off); off += (size_t)SS * 32 * 4;
  f16* hs16 = (f16*)(ws + off); off += (size_t)MTOT * HH * 2;
  f16* wq16 = (f16*)(ws + off); off += (size_t)NQKV * HH * 2;
  f16* wo16 = (f16*)(ws + off); off += (size_t)HH * HH * 2;
  f16* qf = (f16*)(ws + off); off += (size_t)MTOT * HH * 2;
  f16* kf = (f16*)(ws + off); off += (size_t)MTOT * HH * 2;
  f16* vf = (f16*)(ws + off); off += (size_t)MTOT * HH * 2;
  f16* af = (f16*)(ws + off); off += (size_t)MTOT * HH * 2;

  cvt_kernel<<<(MTOT * HH / 4 + 255) / 256, 256, 0, stream>>>(hs, hs16, MTOT * HH / 4);
  cvt_kernel<<<(NQKV * HH / 4 + 255) / 256, 256, 0, stream>>>(Wqkv, wq16, NQKV * HH / 4);
  cvt_kernel<<<(HH * HH / 4 + 255) / 256, 256, 0, stream>>>(Wo, wo16, HH * HH / 4);
  rope_table_kernel<<<(SS * 32 + 255) / 256, 256, 0, stream>>>(ctab, stab);

  // 1. QKV projection + fused RoPE/scale -> q/k/v f16
  gemm_f16<1><<<(MTOT / 128) * (NQKV / 128), 256, 0, stream>>>(
      hs16, wq16, nullptr, qf, kf, vf, pos, ctab, stab, MTOT / 128, NQKV, HH);
  // 2. Attention
  attn_kernel<<<BB * NHEADS * (SS / AQT), 256, 0, stream>>>(qf, kf, vf, af);
  // 3. Output projection
  gemm_f16<0><<<(MTOT / 128) * (HH / 128), 256, 0, stream>>>(
      af, wo16, out, nullptr, nullptr, nullptr, nullptr, nullptr, nullptr,
      MTOT / 128, HH, HH);
}

// Round 10
// 121.204 us; speedup vs baseline: 1.2149x; 1.2149x over previous
//
#include <hip/hip_runtime.h>
#include <hip/hip_bf16.h>
#include <math.h>

#define BB 2
#define SS 4096
#define HH 768
#define NHEADS 12
#define MTOT (BB*SS)     // 8192
#define NQKV (3*HH)      // 2304

typedef _Float16 f16;
typedef __attribute__((ext_vector_type(8))) _Float16 f16x8;
typedef __attribute__((ext_vector_type(4))) _Float16 f16x4;
typedef __attribute__((ext_vector_type(4))) float f32x4;

__device__ __forceinline__ void gld_lds16(const void* g, void* l) {
  __builtin_amdgcn_global_load_lds(
      (const __attribute__((address_space(1))) unsigned int*)g,
      (__attribute__((address_space(3))) unsigned int*)l, 16, 0, 0);
}

// ---------------- f32 -> f16 convert -------------------------------------
__global__ __launch_bounds__(256)
void cvt_kernel(const float* __restrict__ src, f16* __restrict__ dst, int n4) {
  int i = blockIdx.x * 256 + threadIdx.x;
  if (i >= n4) return;
  float4 v = reinterpret_cast<const float4*>(src)[i];
  f16x4 o;
  o[0] = (f16)v.x; o[1] = (f16)v.y; o[2] = (f16)v.z; o[3] = (f16)v.w;
  reinterpret_cast<f16x4*>(dst)[i] = o;
}

// ---------------- RoPE cos/sin table (f64 phase) -------------------------
__global__ void rope_table_kernel(float* __restrict__ ctab, float* __restrict__ stab) {
  int idx = blockIdx.x * 256 + threadIdx.x;   // 4096*32
  if (idx >= SS * 32) return;
  int s = idx >> 5;
  int j = idx & 31;
  const double r = 0.7498942093324559;  // 10000^(-1/32)
  double inv = 1.0;
  for (int t = 0; t < j; ++t) inv *= r;
  double ph = (double)s * inv;
  const double TWO_PI = 6.283185307179586;
  double red = ph - TWO_PI * floor(ph / TWO_PI);
  float rf = (float)red;
  ctab[idx] = cosf(rf);
  stab[idx] = sinf(rf);
}

// ---------------- f16 MFMA GEMM ------------------------------------------
// BK=32, 3-buffer, ONE barrier/step, counted vmcnt, chunk swizzle (R8 best),
// PLUS M-chunked XCD swizzle: each XCD owns a contiguous 8-M-tile chunk so
// its A-panel (1.6 MB) + W-slices stay L2-resident (4 MB/XCD) -> stage loads
// are L2 hits and the depth-2 prefetch fully covers their latency.
template<int EPI>
__global__ __launch_bounds__(256)
void gemm_f16(const f16* __restrict__ A, const f16* __restrict__ Bw,
              float* __restrict__ C,
              f16* __restrict__ Oq, f16* __restrict__ Ok, f16* __restrict__ Ov,
              const int* __restrict__ pos,
              const float* __restrict__ ctab, const float* __restrict__ stab,
              int Mtiles, int N, int K) {
  __shared__ __align__(16) f16 As[3][128][32];   // 24 KB
  __shared__ __align__(16) f16 Bs[3][128][32];   // 24 KB
  const int tid = threadIdx.x;
  const int lane = tid & 63;
  const int w = tid >> 6;
  const int wr = w >> 1, wc = w & 1;

  // M-chunked XCD swizzle (requires gridDim%8==0, Mtiles%8==0; both hold)
  const int bid = blockIdx.x;
  const int xcd = bid & 7;
  const int idx = bid >> 3;
  const int mch = Mtiles >> 3;                 // 8 M-tiles per XCD chunk
  const int bm = (xcd * mch + (idx % mch)) * 128;
  const int bn = (idx / mch) * 128;

  f32x4 acc[4][4] = {};

  const int l4 = lane >> 2;          // staging row-sub (0..15)
  const int lk = lane & 3;           // staging chunk slot (0..3)
  const int srow = w * 32;
  const int fr = lane & 15;          // fragment row within 16
  const int fst = (l4 >> 1) & 3;     // staging swizzle f(row)
  const int pc = (((lane >> 4) ^ ((fr >> 1) & 3)) * 8);  // read phys chunk

  // stage K-chunk k0 into LDS buffer `buf` (exactly 4 gld_lds per thread)
  auto stage = [&](int buf, int k0) {
#pragma unroll
    for (int i = 0; i < 2; ++i) {
      int row = srow + i * 16 + l4;
      gld_lds16(A + (size_t)(bm + row) * K + k0 + (lk ^ fst) * 8,
                (char*)&As[0][0][0] + buf * 8192 + w * 2048 + i * 1024 + lane * 16);
      gld_lds16(Bw + (size_t)(bn + row) * K + k0 + (lk ^ fst) * 8,
                (char*)&Bs[0][0][0] + buf * 8192 + w * 2048 + i * 1024 + lane * 16);
    }
  };
  auto compute = [&](int buf) {
    f16x8 av[4], bv[4];
#pragma unroll
    for (int m = 0; m < 4; ++m)
      av[m] = *reinterpret_cast<const f16x8*>(&As[buf][wr * 64 + m * 16 + fr][pc]);
#pragma unroll
    for (int n = 0; n < 4; ++n)
      bv[n] = *reinterpret_cast<const f16x8*>(&Bs[buf][wc * 64 + n * 16 + fr][pc]);
    __builtin_amdgcn_s_setprio(1);
#pragma unroll
    for (int m = 0; m < 4; ++m)
#pragma unroll
      for (int n = 0; n < 4; ++n)
        acc[m][n] = __builtin_amdgcn_mfma_f32_16x16x32_f16(av[m], bv[n],
                                                           acc[m][n], 0, 0, 0);
    __builtin_amdgcn_s_setprio(0);
  };

  const int T = K >> 5;   // 24 for K=768
  stage(0, 0);
  stage(1, 32);
  for (int t = 0; t < T; ++t) {
    // wait for stage t (the up-to-4 younger loads of stage t+1 stay in flight)
    if (t == T - 1)
      asm volatile("s_waitcnt vmcnt(0)" ::: "memory");
    else
      asm volatile("s_waitcnt vmcnt(4)" ::: "memory");
    __builtin_amdgcn_s_barrier();
    __builtin_amdgcn_sched_barrier(0);
    if (t + 2 < T) stage((t + 2) % 3, (t + 2) << 5);
    compute(t % 3);
  }

  const int cl = lane & 15;
  const int rg = lane >> 4;
  if (EPI == 0) {
#pragma unroll
    for (int m = 0; m < 4; ++m)
#pragma unroll
      for (int n = 0; n < 4; ++n)
#pragma unroll
        for (int r = 0; r < 4; ++r) {
          int row = bm + wr * 64 + m * 16 + rg * 4 + r;
          int col = bn + wc * 64 + n * 16 + cl;
          C[(size_t)row * N + col] = acc[m][n][r];
        }
  } else {
    const int sec = bn / HH;        // 0=q 1=k 2=v (uniform per block)
    f16* dst = (sec == 0) ? Oq : ((sec == 1) ? Ok : Ov);
    const int hb = bn - sec * HH + wc * 64;
#pragma unroll
    for (int m = 0; m < 4; ++m)
#pragma unroll
      for (int r = 0; r < 4; ++r) {
        int row = bm + wr * 64 + m * 16 + rg * 4 + r;
        if (sec < 2) {
          int s = pos[row];
#pragma unroll
          for (int n = 0; n < 4; ++n) {
            int hd = hb + n * 16 + cl;
            int d = hd & 63;
            int d2 = d & 31;
            float c = ctab[s * 32 + d2];
            float sn = stab[s * 32 + d2];
            float val = acc[m][n][r];
            float pv = acc[m][n ^ 2][r];
            val = (d < 32) ? (val * c - pv * sn) : (val * c + pv * sn);
            if (sec == 0) val *= 0.125f;
            dst[(size_t)row * HH + hd] = (f16)val;
          }
        } else {
#pragma unroll
          for (int n = 0; n < 4; ++n)
            dst[(size_t)row * HH + hb + n * 16 + cl] = (f16)acc[m][n][r];
        }
      }
  }
}

// ---------------- MFMA sliding-window attention --------------------------
// Block: (b, h, 64-query tile). Window keys: [q0-64, q0+127] = 192 rows.
#define AQT 64
#define AKT 192
#define KP 72     // K/Q row pad (f16): 144 B rows
#define VP 200    // Vt / P row pad: 400 B rows

__global__ __launch_bounds__(256)
void attn_kernel(const f16* __restrict__ qg, const f16* __restrict__ kg,
                 const f16* __restrict__ vg, f16* __restrict__ og) {
  __shared__ __align__(16) f16 Qs[AQT][KP];     // 9216 B
  __shared__ __align__(16) f16 Ks[AKT][KP];     // 27648 B, reused for P[64][VP]
  __shared__ __align__(16) f16 Vs[64][VP];      // 25600 B (transposed V)
  __shared__ float sums[AQT];

  const int tid = threadIdx.x;
  const int lane = tid & 63;
  const int wq = tid >> 6;
  const int l15 = lane & 15, g = lane >> 4;
  const int blk = blockIdx.x;
  const int qt = blk % (SS / AQT);
  const int h = (blk / (SS / AQT)) % NHEADS;
  const int b = blk / ((SS / AQT) * NHEADS);
  const int q0 = qt * AQT;
  const int kbase = q0 - 64;

  // ---- stage Q (64x64), K (192x64), V transposed (64x192) ----
#pragma unroll
  for (int i = 0; i < 2; ++i) {
    int idx = tid + i * 256;
    int r = idx >> 3, ch = idx & 7;
    f16x8 v = *reinterpret_cast<const f16x8*>(
        &qg[((size_t)(b * SS + q0 + r)) * HH + h * 64 + ch * 8]);
    *reinterpret_cast<f16x8*>(&Qs[r][ch * 8]) = v;
  }
#pragma unroll
  for (int i = 0; i < 6; ++i) {
    int idx = tid + i * 256;
    int r = idx >> 3, ch = idx & 7;
    int kglob = kbase + r;
    f16x8 v = {};
    if (kglob >= 0 && kglob < SS)
      v = *reinterpret_cast<const f16x8*>(
          &kg[((size_t)(b * SS + kglob)) * HH + h * 64 + ch * 8]);
    *reinterpret_cast<f16x8*>(&Ks[r][ch * 8]) = v;
  }
#pragma unroll
  for (int i = 0; i < 6; ++i) {
    int idx = tid + i * 256;
    int r = idx >> 3, ch = idx & 7;
    int kglob = kbase + r;
    f16x8 v = {};
    if (kglob >= 0 && kglob < SS)
      v = *reinterpret_cast<const f16x8*>(
          &vg[((size_t)(b * SS + kglob)) * HH + h * 64 + ch * 8]);
#pragma unroll
    for (int j = 0; j < 8; ++j) Vs[ch * 8 + j][r] = v[j];
  }
  __syncthreads();

  // ---- S^T = K . Q^T ----
  f32x4 accs[12] = {};
#pragma unroll
  for (int kd = 0; kd < 2; ++kd) {
    f16x8 bq = *reinterpret_cast<const f16x8*>(&Qs[wq * 16 + l15][kd * 32 + g * 8]);
#pragma unroll
    for (int f = 0; f < 12; ++f) {
      f16x8 ak = *reinterpret_cast<const f16x8*>(&Ks[f * 16 + l15][kd * 32 + g * 8]);
      accs[f] = __builtin_amdgcn_mfma_f32_16x16x32_f16(ak, bq, accs[f], 0, 0, 0);
    }
  }
  __syncthreads();   // Ks becomes P storage

  // ---- softmax over keys; lane owns column q = wq*16+l15 ----
  const int qloc = wq * 16 + l15;
  float mx = -1e30f;
#pragma unroll
  for (int f = 0; f < 12; ++f)
#pragma unroll
    for (int r = 0; r < 4; ++r) {
      int key = f * 16 + g * 4 + r;
      int kglob = kbase + key;
      bool valid = (key >= qloc) && (key <= qloc + 128) && (kglob >= 0) && (kglob < SS);
      float s = valid ? accs[f][r] : -1e30f;
      accs[f][r] = s;
      mx = fmaxf(mx, s);
    }
  mx = fmaxf(mx, __shfl_xor(mx, 16));
  mx = fmaxf(mx, __shfl_xor(mx, 32));
  f16* Ps = &Ks[0][0];
  float sum = 0.f;
#pragma unroll
  for (int f = 0; f < 12; ++f) {
    float p0 = __expf(accs[f][0] - mx);
    float p1 = __expf(accs[f][1] - mx);
    float p2 = __expf(accs[f][2] - mx);
    float p3 = __expf(accs[f][3] - mx);
    sum += (p0 + p1) + (p2 + p3);
    f16x4 pk;
    pk[0] = (f16)p0; pk[1] = (f16)p1; pk[2] = (f16)p2; pk[3] = (f16)p3;
    *reinterpret_cast<f16x4*>(&Ps[(size_t)qloc * VP + f * 16 + g * 4]) = pk;
  }
  sum += __shfl_xor(sum, 16);
  sum += __shfl_xor(sum, 32);
  if (g == 0) sums[qloc] = sum;

  // ---- O = P . V ----
  f32x4 acco[4] = {};
#pragma unroll
  for (int ks = 0; ks < 6; ++ks) {
    f16x8 pa = *reinterpret_cast<const f16x8*>(&Ps[(size_t)(wq * 16 + l15) * VP + ks * 32 + g * 8]);
#pragma unroll
    for (int n = 0; n < 4; ++n) {
      f16x8 bv = *reinterpret_cast<const f16x8*>(&Vs[n * 16 + l15][ks * 32 + g * 8]);
      acco[n] = __builtin_amdgcn_mfma_f32_16x16x32_f16(pa, bv, acco[n], 0, 0, 0);
    }
  }
#pragma unroll
  for (int r = 0; r < 4; ++r) {
    int qo = wq * 16 + g * 4 + r;
    float inv = 1.0f / sums[qo];
    size_t base = ((size_t)(b * SS + q0 + qo)) * HH + h * 64;
#pragma unroll
    for (int n = 0; n < 4; ++n)
      og[base + n * 16 + l15] = (f16)(acco[n][r] * inv);
  }
}

extern "C" void kernel_launch(void* const* d_in, const int* in_sizes, int n_in,
                              void* d_out, int out_size, void* d_ws, size_t ws_size,
                              hipStream_t stream) {
  const float* hs = (const float*)d_in[0];
  const int* pos = (const int*)d_in[3];
  const float* Wqkv = (const float*)d_in[4];
  const float* Wo = (const float*)d_in[5];
  float* out = (float*)d_out;

  uint8_t* ws = (uint8_t*)d_ws;
  size_t off = 0;
  float* ctab = (float*)(ws + off); off += (size_t)SS * 32 * 4;
  float* stab = (float*)(ws + off); off += (size_t)SS * 32 * 4;
  f16* hs16 = (f16*)(ws + off); off += (size_t)MTOT * HH * 2;
  f16* wq16 = (f16*)(ws + off); off += (size_t)NQKV * HH * 2;
  f16* wo16 = (f16*)(ws + off); off += (size_t)HH * HH * 2;
  f16* qf = (f16*)(ws + off); off += (size_t)MTOT * HH * 2;
  f16* kf = (f16*)(ws + off); off += (size_t)MTOT * HH * 2;
  f16* vf = (f16*)(ws + off); off += (size_t)MTOT * HH * 2;
  f16* af = (f16*)(ws + off); off += (size_t)MTOT * HH * 2;

  cvt_kernel<<<(MTOT * HH / 4 + 255) / 256, 256, 0, stream>>>(hs, hs16, MTOT * HH / 4);
  cvt_kernel<<<(NQKV * HH / 4 + 255) / 256, 256, 0, stream>>>(Wqkv, wq16, NQKV * HH / 4);
  cvt_kernel<<<(HH * HH / 4 + 255) / 256, 256, 0, stream>>>(Wo, wo16, HH * HH / 4);
  rope_table_kernel<<<(SS * 32 + 255) / 256, 256, 0, stream>>>(ctab, stab);

  // 1. QKV projection + fused RoPE/scale -> q/k/v f16
  gemm_f16<1><<<(MTOT / 128) * (NQKV / 128), 256, 0, stream>>>(
      hs16, wq16, nullptr, qf, kf, vf, pos, ctab, stab, MTOT / 128, NQKV, HH);
  // 2. Attention
  attn_kernel<<<BB * NHEADS * (SS / AQT), 256, 0, stream>>>(qf, kf, vf, af);
  // 3. Output projection
  gemm_f16<0><<<(MTOT / 128) * (HH / 128), 256, 0, stream>>>(
      af, wo16, out, nullptr, nullptr, nullptr, nullptr, nullptr, nullptr,
      MTOT / 128, HH, HH);
}